// Round 4
// baseline (286.216 us; speedup 1.0000x reference)
//
#include <hip/hip_runtime.h>
#include <stdint.h>

#define NUM_HEADS 12
#define HEAD_DIM 64
#define EMB 768
#define SEQ 4096
#define BATCH 2
#define ROWS (BATCH*SEQ)     // 8192
#define DQKV (3*EMB)         // 2304

typedef __attribute__((ext_vector_type(8))) __bf16 bf16x8;
typedef __attribute__((ext_vector_type(4))) float floatx4;

static __device__ __forceinline__ unsigned short f2bf(float f) {
  unsigned int u = __float_as_uint(f);
  u += 0x7FFFu + ((u >> 16) & 1u);          // round-to-nearest-even
  return (unsigned short)(u >> 16);
}

// truncating pack: two fp32 -> bf16x2 dword {hi(b),hi(a)} — 1 v_perm, no adds
static __device__ __forceinline__ unsigned int pack_bf2_trunc(float a, float b) {
  return __builtin_amdgcn_perm(__float_as_uint(b), __float_as_uint(a), 0x07060302u);
}

static __device__ __forceinline__ void async_cp16(void* lds, const void* g) {
  __builtin_amdgcn_global_load_lds(
      (__attribute__((address_space(1))) void*)(g),
      (__attribute__((address_space(3))) void*)(lds), 16, 0, 0);
}

// ---------------- fp32 -> bf16 convert ----------------
__global__ __launch_bounds__(256) void cvt_bf16_kernel(
    const float* __restrict__ src, unsigned short* __restrict__ dst, int n4) {
  int i = blockIdx.x * blockDim.x + threadIdx.x;
  if (i >= n4) return;
  float4 v = ((const float4*)src)[i];
  ushort4 o;
  o.x = f2bf(v.x); o.y = f2bf(v.y); o.z = f2bf(v.z); o.w = f2bf(v.w);
  ((ushort4*)dst)[i] = o;
}

// ---------------- Q/K projection GEMM (operand-swapped) ----------------
// acc = mfma(W_frag, X_frag): D rows = output features (4 consecutive/lane)
// -> vectorized ushort4 stores into [b,h,n,64]. grid (64, 12).
__global__ __launch_bounds__(256) void qk_gemm_kernel(
    const unsigned short* __restrict__ xb, const unsigned short* __restrict__ wb,
    const float* __restrict__ bias,
    unsigned short* __restrict__ Qb, unsigned short* __restrict__ Kb) {
  __shared__ unsigned short As[128 * 64];
  __shared__ unsigned short Bs[128 * 64];
  const int t = threadIdx.x;
  const int lane = t & 63;
  const int w = t >> 6;
  const int wm = w >> 1, wn = w & 1;
  const int fr = lane & 15, fq = lane >> 4;
  const int fx = fr & 7;
  const int m0 = blockIdx.x * 128;
  const int n0 = blockIdx.y * 128;
  const int lr = t >> 3;          // 0..31
  const int sc = t & 7;           // chunk col 0..7

  floatx4 acc[4][4];
#pragma unroll
  for (int i = 0; i < 4; ++i)
#pragma unroll
    for (int j = 0; j < 4; ++j) acc[i][j] = (floatx4)(0.0f);

  for (int k0 = 0; k0 < EMB; k0 += 64) {
    __syncthreads();
#pragma unroll
    for (int i = 0; i < 4; ++i) {
      const int rr = i*32 + lr;
      const int cg = ((sc ^ (lr & 7)) * 8);
      async_cp16(&As[rr*64 + sc*8], &xb[(size_t)(m0 + rr)*EMB + k0 + cg]);
      async_cp16(&Bs[rr*64 + sc*8], &wb[(size_t)(n0 + rr)*EMB + k0 + cg]);
    }
    __syncthreads();
#pragma unroll
    for (int ks = 0; ks < 2; ++ks) {
      bf16x8 af[4], bfr[4];
#pragma unroll
      for (int i = 0; i < 4; ++i)
        af[i] = *(const bf16x8*)&As[(wm*64 + i*16 + fr)*64 + (((ks*4+fq) ^ fx)*8)];
#pragma unroll
      for (int j = 0; j < 4; ++j)
        bfr[j] = *(const bf16x8*)&Bs[(wn*64 + j*16 + fr)*64 + (((ks*4+fq) ^ fx)*8)];
#pragma unroll
      for (int i = 0; i < 4; ++i)
#pragma unroll
        for (int j = 0; j < 4; ++j)
          acc[i][j] = __builtin_amdgcn_mfma_f32_16x16x32_bf16(bfr[j], af[i], acc[i][j], 0, 0, 0);
    }
  }

  // D layout: row (feature) = j*16 + fq*4 + reg, col (x row) = i*16 + fr.
  const int sel = n0 / EMB;                       // 0=Q 1=K (uniform/block)
  const float qscale = 0.125f * 1.4426950408889634f;  // 1/sqrt(64)*log2(e)
  const float sc2 = (sel == 0) ? qscale : 1.0f;
  unsigned short* dst = (sel == 0) ? Qb : Kb;
#pragma unroll
  for (int i = 0; i < 4; ++i) {
    const int mr = m0 + wm*64 + i*16 + fr;        // x row
    const int b = mr / SEQ;
    const int nn = mr - b*SEQ;
#pragma unroll
    for (int j = 0; j < 4; ++j) {
      const int og = n0 + wn*64 + j*16 + fq*4;    // feature base (4 consecutive)
      const int oo = og - sel*EMB;
      const int hh = oo >> 6, dd = oo & 63;
      const float4 bv = *(const float4*)&bias[og];
      ushort4 pk;
      pk.x = f2bf((acc[i][j][0] + bv.x) * sc2);
      pk.y = f2bf((acc[i][j][1] + bv.y) * sc2);
      pk.z = f2bf((acc[i][j][2] + bv.z) * sc2);
      pk.w = f2bf((acc[i][j][3] + bv.w) * sc2);
      *(ushort4*)&dst[(((size_t)(b*NUM_HEADS + hh))*SEQ + nn)*HEAD_DIM + dd] = pk;
    }
  }
}

// ---------------- V projection GEMM (natural order) ----------------
// acc = mfma(X_frag, W_frag): D rows = x-rows (4 consecutive nn per lane)
// -> ushort4 stores along Vt's fast dim (nn). grid (64, 6), n0 = 1536+.
__global__ __launch_bounds__(256) void v_gemm_kernel(
    const unsigned short* __restrict__ xb, const unsigned short* __restrict__ wb,
    const float* __restrict__ bias, unsigned short* __restrict__ Vt) {
  __shared__ unsigned short As[128 * 64];
  __shared__ unsigned short Bs[128 * 64];
  const int t = threadIdx.x;
  const int lane = t & 63;
  const int w = t >> 6;
  const int wm = w >> 1, wn = w & 1;
  const int fr = lane & 15, fq = lane >> 4;
  const int fx = fr & 7;
  const int m0 = blockIdx.x * 128;
  const int n0 = 2*EMB + blockIdx.y * 128;
  const int lr = t >> 3;
  const int sc = t & 7;

  floatx4 acc[4][4];
#pragma unroll
  for (int i = 0; i < 4; ++i)
#pragma unroll
    for (int j = 0; j < 4; ++j) acc[i][j] = (floatx4)(0.0f);

  for (int k0 = 0; k0 < EMB; k0 += 64) {
    __syncthreads();
#pragma unroll
    for (int i = 0; i < 4; ++i) {
      const int rr = i*32 + lr;
      const int cg = ((sc ^ (lr & 7)) * 8);
      async_cp16(&As[rr*64 + sc*8], &xb[(size_t)(m0 + rr)*EMB + k0 + cg]);
      async_cp16(&Bs[rr*64 + sc*8], &wb[(size_t)(n0 + rr)*EMB + k0 + cg]);
    }
    __syncthreads();
#pragma unroll
    for (int ks = 0; ks < 2; ++ks) {
      bf16x8 af[4], bfr[4];
#pragma unroll
      for (int i = 0; i < 4; ++i)
        af[i] = *(const bf16x8*)&As[(wm*64 + i*16 + fr)*64 + (((ks*4+fq) ^ fx)*8)];
#pragma unroll
      for (int j = 0; j < 4; ++j)
        bfr[j] = *(const bf16x8*)&Bs[(wn*64 + j*16 + fr)*64 + (((ks*4+fq) ^ fx)*8)];
#pragma unroll
      for (int i = 0; i < 4; ++i)
#pragma unroll
        for (int j = 0; j < 4; ++j)
          acc[i][j] = __builtin_amdgcn_mfma_f32_16x16x32_bf16(af[i], bfr[j], acc[i][j], 0, 0, 0);
    }
  }

  // D layout: row (x row) = i*16 + fq*4 + reg, col (feature) = j*16 + fr.
#pragma unroll
  for (int i = 0; i < 4; ++i) {
    const int mr = m0 + wm*64 + i*16 + fq*4;      // x row base (4 consecutive)
    const int b = mr / SEQ;
    const int nn = mr - b*SEQ;
#pragma unroll
    for (int j = 0; j < 4; ++j) {
      const int feat = n0 + wn*64 + j*16 + fr;
      const int oo = feat - 2*EMB;
      const int hh = oo >> 6, dd = oo & 63;
      const float bv = bias[feat];
      ushort4 pk;
      pk.x = f2bf(acc[i][j][0] + bv);
      pk.y = f2bf(acc[i][j][1] + bv);
      pk.z = f2bf(acc[i][j][2] + bv);
      pk.w = f2bf(acc[i][j][3] + bv);
      *(ushort4*)&Vt[(((size_t)(b*NUM_HEADS + hh))*HEAD_DIM + dd)*SEQ + nn] = pk;
    }
  }
}

// ---------------- flash attention, S^T formulation ----------------
// grid (SEQ/128, BATCH*NUM_HEADS), 512 threads = 8 waves x 16 q-rows.
// 3 blocks/CU x 8 waves = 24 waves/CU: softmax VALU segments of one wave
// hide under MFMAs of the other five on the same SIMD.
__global__ __launch_bounds__(512, 6) void attn_kernel(
    const unsigned short* __restrict__ Qb, const unsigned short* __restrict__ Kb,
    const unsigned short* __restrict__ Vt, unsigned short* __restrict__ Oo) {
  __shared__ unsigned short Ks[128 * 64];   // [key][d], 8 chunks/row, swizzled
  __shared__ unsigned short Vs[64 * 128];   // [d][key], 16 chunks/row, swizzled
  const int t = threadIdx.x;
  const int lane = t & 63;
  const int w = t >> 6;                     // 0..7
  const int fr = lane & 15, fq = lane >> 4;
  const int fx = fr & 7;
  const int bh = blockIdx.y;
  const int q0 = blockIdx.x * 128 + w * 16;

  // Q fragment (B-operand of S^T): rows q0+fr, scale pre-folded.
  const size_t qoff = ((size_t)bh * SEQ + q0 + fr) * HEAD_DIM;
  bf16x8 aq0 = *(const bf16x8*)&Qb[qoff + fq*8];
  bf16x8 aq1 = *(const bf16x8*)&Qb[qoff + 32 + fq*8];

  union { unsigned int u[4]; bf16x8 b; } onesu;
  onesu.u[0] = onesu.u[1] = onesu.u[2] = onesu.u[3] = 0x3F803F80u;
  const bf16x8 onesb = onesu.b;

  floatx4 o[4];
  floatx4 lsum = (floatx4)(0.f);
#pragma unroll
  for (int d = 0; d < 4; ++d) o[d] = (floatx4)(0.f);

  const size_t kb = (size_t)bh * SEQ * HEAD_DIM;
  const size_t vb = (size_t)bh * HEAD_DIM * SEQ;

  for (int kc = 0; kc < SEQ; kc += 128) {
    __syncthreads();
#pragma unroll
    for (int i = 0; i < 2; ++i) {           // Ks: 1024 chunks, rows of 8
      const int chunk = i*512 + t;
      const int r = chunk >> 3, c = chunk & 7;
      async_cp16(&Ks[chunk*8], &Kb[kb + (size_t)(kc + r)*HEAD_DIM + ((c ^ (r&7))*8)]);
    }
#pragma unroll
    for (int i = 0; i < 2; ++i) {           // Vs: 1024 chunks, rows of 16
      const int chunk = i*512 + t;
      const int r = chunk >> 4, c = chunk & 15;
      async_cp16(&Vs[chunk*8], &Vt[vb + (size_t)r*SEQ + kc + ((c ^ (r&7))*8)]);
    }
    __syncthreads();

#pragma unroll
    for (int J = 0; J < 4; ++J) {           // 32-key chunks
      floatx4 z[2];
#pragma unroll
      for (int jj = 0; jj < 2; ++jj) {
        const int row = (J*2 + jj)*16 + fr; // key row in Ks
        bf16x8 k0 = *(const bf16x8*)&Ks[row*64 + ((fq ^ fx)*8)];
        bf16x8 k1 = *(const bf16x8*)&Ks[row*64 + (((fq+4) ^ fx)*8)];
        floatx4 accz = (floatx4)(0.f);
        accz = __builtin_amdgcn_mfma_f32_16x16x32_bf16(k0, aq0, accz, 0, 0, 0);
        accz = __builtin_amdgcn_mfma_f32_16x16x32_bf16(k1, aq1, accz, 0, 0, 0);
        z[jj] = accz;                       // S^T: key=16(2J+jj)+fq*4+r, q=fr
      }
      // exp2 + truncate-pack to PV A-fragment (register-only transpose)
      float e0 = __builtin_amdgcn_exp2f(z[0][0]);
      float e1 = __builtin_amdgcn_exp2f(z[0][1]);
      float e2 = __builtin_amdgcn_exp2f(z[0][2]);
      float e3 = __builtin_amdgcn_exp2f(z[0][3]);
      float e4 = __builtin_amdgcn_exp2f(z[1][0]);
      float e5 = __builtin_amdgcn_exp2f(z[1][1]);
      float e6 = __builtin_amdgcn_exp2f(z[1][2]);
      float e7 = __builtin_amdgcn_exp2f(z[1][3]);
      union { unsigned int u[4]; bf16x8 b; } cv;
      cv.u[0] = pack_bf2_trunc(e0, e1);
      cv.u[1] = pack_bf2_trunc(e2, e3);
      cv.u[2] = pack_bf2_trunc(e4, e5);
      cv.u[3] = pack_bf2_trunc(e6, e7);
      const bf16x8 ap = cv.b;
      // l += P * ones  (row-sum on the MFMA pipe; D rows = q like O)
      lsum = __builtin_amdgcn_mfma_f32_16x16x32_bf16(ap, onesb, lsum, 0, 0, 0);
      // PV: O[q][d] += P[q][key] V[key][d] over keys [32J, 32J+32)
#pragma unroll
      for (int dt = 0; dt < 4; ++dt) {
        const int r = dt*16 + fr;           // d row in Vs
        const int c0 = 4*J + (fq >> 1);
        const int c1 = c0 + 2;
        union { ushort4 h[2]; bf16x8 b; } vv;
        vv.h[0] = *(const ushort4*)&Vs[r*128 + ((c0 ^ fx)*8) + (fq&1)*4];
        vv.h[1] = *(const ushort4*)&Vs[r*128 + ((c1 ^ fx)*8) + (fq&1)*4];
        o[dt] = __builtin_amdgcn_mfma_f32_16x16x32_bf16(ap, vv.b, o[dt], 0, 0, 0);
      }
    }
  }

  const int b = bh / NUM_HEADS, hh = bh - b*NUM_HEADS;
#pragma unroll
  for (int r4 = 0; r4 < 4; ++r4) {
    const float li = 1.0f / lsum[r4];       // l[q=fq*4+r4] — same layout as O
    const size_t obase = ((size_t)b*SEQ + q0 + fq*4 + r4)*EMB + hh*HEAD_DIM;
#pragma unroll
    for (int dt = 0; dt < 4; ++dt)
      Oo[obase + dt*16 + fr] = f2bf(o[dt][r4] * li);
  }
}

// ---------------- residual + LayerNorm (att in bf16) ----------------
__global__ __launch_bounds__(256) void ln_kernel(
    const float* __restrict__ x, const unsigned short* __restrict__ att,
    const float* __restrict__ gamma, const float* __restrict__ beta,
    float* __restrict__ out) {
  const int row = blockIdx.x;
  const size_t base = (size_t)row * EMB;
  const int t = threadIdx.x;
  float v[3];
  float s = 0.f, s2 = 0.f;
#pragma unroll
  for (int k = 0; k < 3; ++k) {
    const int c = t + k*256;
    float a = __uint_as_float(((unsigned int)att[base + c]) << 16);
    float val = x[base + c] + a;
    v[k] = val; s += val; s2 += val*val;
  }
#pragma unroll
  for (int off = 32; off > 0; off >>= 1) {
    s  += __shfl_down(s,  off);
    s2 += __shfl_down(s2, off);
  }
  __shared__ float red[8];
  if ((t & 63) == 0) { red[t >> 6] = s; red[4 + (t >> 6)] = s2; }
  __syncthreads();
  const float S  = red[0] + red[1] + red[2] + red[3];
  const float S2 = red[4] + red[5] + red[6] + red[7];
  const float mean = S * (1.0f / EMB);
  const float var  = S2 * (1.0f / EMB) - mean * mean;
  const float rstd = rsqrtf(var + 1e-5f);
#pragma unroll
  for (int k = 0; k < 3; ++k) {
    const int c = t + k*256;
    out[base + c] = (v[k] - mean) * rstd * gamma[c] + beta[c];
  }
}

extern "C" void kernel_launch(void* const* d_in, const int* in_sizes, int n_in,
                              void* d_out, int out_size, void* d_ws, size_t ws_size,
                              hipStream_t stream) {
  const float* x      = (const float*)d_in[0];
  const float* w_qkv  = (const float*)d_in[1];
  const float* b_qkv  = (const float*)d_in[2];
  const float* gamma  = (const float*)d_in[3];
  const float* beta   = (const float*)d_in[4];
  float* out = (float*)d_out;

  unsigned short* xb = (unsigned short*)d_ws;                 // 8192*768 bf16
  unsigned short* wb = xb + (size_t)ROWS * EMB;               // 2304*768 bf16
  unsigned short* Qb = wb + (size_t)DQKV * EMB;               // [b,h,n,64] bf16 (scaled)
  unsigned short* Kb = Qb + (size_t)ROWS * EMB;               // [b,h,n,64] bf16
  unsigned short* Vt = Kb + (size_t)ROWS * EMB;               // [b,h,64,n] bf16
  unsigned short* att = Vt + (size_t)ROWS * EMB;              // [b,n,768] bf16

  cvt_bf16_kernel<<<(ROWS*EMB/4 + 255)/256, 256, 0, stream>>>(x, xb, ROWS*EMB/4);
  cvt_bf16_kernel<<<(DQKV*EMB/4 + 255)/256, 256, 0, stream>>>(w_qkv, wb, DQKV*EMB/4);
  qk_gemm_kernel<<<dim3(ROWS/128, 2*EMB/128), 256, 0, stream>>>(xb, wb, b_qkv, Qb, Kb);
  v_gemm_kernel<<<dim3(ROWS/128, EMB/128), 256, 0, stream>>>(xb, wb, b_qkv, Vt);
  attn_kernel<<<dim3(SEQ/128, BATCH*NUM_HEADS), 512, 0, stream>>>(Qb, Kb, Vt, att);
  ln_kernel<<<ROWS, 256, 0, stream>>>(x, att, gamma, beta, out);
}